// Round 1
// baseline (300.058 us; speedup 1.0000x reference)
//
#include <hip/hip_runtime.h>

typedef _Float16 f16;
typedef _Float16 f16x8 __attribute__((ext_vector_type(8)));
typedef float f32x4 __attribute__((ext_vector_type(4)));

#define MFMA16(a,b,c) __builtin_amdgcn_mfma_f32_16x16x32_f16((a),(b),(c),0,0,0)

// ---------- transpose + split: f32 in[R][C] -> fp16 hi/lo out[C][R] ----------
__global__ __launch_bounds__(256) void k_tsplit(const float* __restrict__ in,
                                                f16* __restrict__ oh, f16* __restrict__ ol,
                                                int R, int C) {
  __shared__ float t[64][65];
  int c0 = blockIdx.x * 64, r0 = blockIdx.y * 64;
#pragma unroll
  for (int i = 0; i < 16; ++i) {
    int idx = threadIdx.x + i * 256;
    int r = idx >> 6, c = idx & 63;
    t[r][c] = in[(size_t)(r0 + r) * C + (c0 + c)];
  }
  __syncthreads();
#pragma unroll
  for (int i = 0; i < 16; ++i) {
    int idx = threadIdx.x + i * 256;
    int c = idx >> 6, r = idx & 63;   // consecutive threads vary r -> coalesced writes
    float v = t[r][c];
    f16 h = (f16)v;
    f16 l = (f16)(v - (float)h);
    size_t o = (size_t)(c0 + c) * R + (r0 + r);
    oh[o] = h;
    ol[o] = l;
  }
}

// ---------- mask bytes: bit j of mb[i] = (x[i*8+j] != 0) ----------
__global__ __launch_bounds__(256) void k_mask(const float* __restrict__ x,
                                              unsigned char* __restrict__ mb) {
  int idx = blockIdx.x * 256 + threadIdx.x;  // total 8192*4096/8 = 4194304
  const f32x4* p = (const f32x4*)(x + (size_t)idx * 8);
  f32x4 a = p[0], b = p[1];
  unsigned m = 0;
  if (a[0] != 0.f) m |= 1u;
  if (a[1] != 0.f) m |= 2u;
  if (a[2] != 0.f) m |= 4u;
  if (a[3] != 0.f) m |= 8u;
  if (b[0] != 0.f) m |= 16u;
  if (b[1] != 0.f) m |= 32u;
  if (b[2] != 0.f) m |= 64u;
  if (b[3] != 0.f) m |= 128u;
  mb[idx] = (unsigned char)m;
}

// ---------- GEMM1: H = relu(X @ W1 + b1), split-fp16 MFMA ----------
// X[8192][4096] f32, W1t hi/lo [256][4096] fp16 (pre-transposed), H hi/lo [8192][256] fp16
__global__ __launch_bounds__(256) void k_gemm1(const float* __restrict__ X,
                                               const f16* __restrict__ Bhg,
                                               const f16* __restrict__ Blg,
                                               const float* __restrict__ b1,
                                               f16* __restrict__ Hh, f16* __restrict__ Hl) {
  __shared__ f16 Ah[64 * 40], Al[64 * 40], Bh[64 * 40], Bl[64 * 40];
  int m0 = blockIdx.x * 64, n0 = blockIdx.y * 64;
  int tid = threadIdx.x;
  int wv = tid >> 6, ln = tid & 63;
  int wr = wv >> 1, wc = wv & 1, lr = ln & 15, lg = ln >> 4;
  int arow = tid >> 2, akoff = (tid & 3) * 8;
  f32x4 acc[2][2] = {};

  for (int k0 = 0; k0 < 4096; k0 += 32) {
    // stage A: 64x32 f32 -> split fp16 hi/lo
    const f32x4* pa = (const f32x4*)(X + (size_t)(m0 + arow) * 4096 + k0 + akoff);
    f32x4 v0 = pa[0], v1 = pa[1];
    f16x8 hv, lv;
#pragma unroll
    for (int j = 0; j < 4; ++j) {
      f16 h0 = (f16)v0[j]; hv[j] = h0; lv[j] = (f16)(v0[j] - (float)h0);
      f16 h1 = (f16)v1[j]; hv[j + 4] = h1; lv[j + 4] = (f16)(v1[j] - (float)h1);
    }
    *(f16x8*)&Ah[arow * 40 + akoff] = hv;
    *(f16x8*)&Al[arow * 40 + akoff] = lv;
    // stage B: [64 n][32 k] fp16 hi/lo (already transposed in ws)
    *(f16x8*)&Bh[arow * 40 + akoff] =
        *(const f16x8*)(Bhg + (size_t)(n0 + arow) * 4096 + k0 + akoff);
    *(f16x8*)&Bl[arow * 40 + akoff] =
        *(const f16x8*)(Blg + (size_t)(n0 + arow) * 4096 + k0 + akoff);
    __syncthreads();

    f16x8 fah[2], fal[2], fbh[2], fbl[2];
#pragma unroll
    for (int fi = 0; fi < 2; ++fi) {
      int r = wr * 32 + fi * 16 + lr;
      fah[fi] = *(const f16x8*)&Ah[r * 40 + lg * 8];
      fal[fi] = *(const f16x8*)&Al[r * 40 + lg * 8];
    }
#pragma unroll
    for (int fj = 0; fj < 2; ++fj) {
      int c = wc * 32 + fj * 16 + lr;
      fbh[fj] = *(const f16x8*)&Bh[c * 40 + lg * 8];
      fbl[fj] = *(const f16x8*)&Bl[c * 40 + lg * 8];
    }
#pragma unroll
    for (int fi = 0; fi < 2; ++fi)
#pragma unroll
      for (int fj = 0; fj < 2; ++fj) {
        acc[fi][fj] = MFMA16(fah[fi], fbh[fj], acc[fi][fj]);
        acc[fi][fj] = MFMA16(fah[fi], fbl[fj], acc[fi][fj]);
        acc[fi][fj] = MFMA16(fal[fi], fbh[fj], acc[fi][fj]);
      }
    __syncthreads();
  }

  // epilogue: bias + relu + split to fp16 hi/lo
#pragma unroll
  for (int fi = 0; fi < 2; ++fi)
#pragma unroll
    for (int fj = 0; fj < 2; ++fj)
#pragma unroll
      for (int r = 0; r < 4; ++r) {
        int row = m0 + wr * 32 + fi * 16 + lg * 4 + r;
        int col = n0 + wc * 32 + fj * 16 + lr;
        float v = acc[fi][fj][r] + b1[col];
        v = v > 0.f ? v : 0.f;
        f16 h = (f16)v;
        Hh[(size_t)row * 256 + col] = h;
        Hl[(size_t)row * 256 + col] = (f16)(v - (float)h);
      }
}

// ---------- GEMM2: F = H @ W2 + b2, masked write + per-tile row sums ----------
__global__ __launch_bounds__(256) void k_gemm2(const f16* __restrict__ Ahg,
                                               const f16* __restrict__ Alg,
                                               const f16* __restrict__ Bhg,
                                               const f16* __restrict__ Blg,
                                               const float* __restrict__ b2,
                                               const unsigned* __restrict__ maskw,
                                               float* __restrict__ out,
                                               float* __restrict__ partials) {
  __shared__ f16 Ah[64 * 40], Al[64 * 40], Bh[64 * 40], Bl[64 * 40];
  __shared__ unsigned mlds[64][2];
  __shared__ float rsum[64][2];
  int m0 = blockIdx.x * 64, n0 = blockIdx.y * 64;
  int tid = threadIdx.x;
  int wv = tid >> 6, ln = tid & 63;
  int wr = wv >> 1, wc = wv & 1, lr = ln & 15, lg = ln >> 4;
  int arow = tid >> 2, akoff = (tid & 3) * 8;

  if (tid < 128) {
    int r = tid >> 1, w = tid & 1;
    mlds[r][w] = maskw[(size_t)(m0 + r) * 128 + (n0 >> 5) + w];
  }

  f32x4 acc[2][2] = {};
  for (int k0 = 0; k0 < 256; k0 += 32) {
    *(f16x8*)&Ah[arow * 40 + akoff] =
        *(const f16x8*)(Ahg + (size_t)(m0 + arow) * 256 + k0 + akoff);
    *(f16x8*)&Al[arow * 40 + akoff] =
        *(const f16x8*)(Alg + (size_t)(m0 + arow) * 256 + k0 + akoff);
    *(f16x8*)&Bh[arow * 40 + akoff] =
        *(const f16x8*)(Bhg + (size_t)(n0 + arow) * 256 + k0 + akoff);
    *(f16x8*)&Bl[arow * 40 + akoff] =
        *(const f16x8*)(Blg + (size_t)(n0 + arow) * 256 + k0 + akoff);
    __syncthreads();

    f16x8 fah[2], fal[2], fbh[2], fbl[2];
#pragma unroll
    for (int fi = 0; fi < 2; ++fi) {
      int r = wr * 32 + fi * 16 + lr;
      fah[fi] = *(const f16x8*)&Ah[r * 40 + lg * 8];
      fal[fi] = *(const f16x8*)&Al[r * 40 + lg * 8];
    }
#pragma unroll
    for (int fj = 0; fj < 2; ++fj) {
      int c = wc * 32 + fj * 16 + lr;
      fbh[fj] = *(const f16x8*)&Bh[c * 40 + lg * 8];
      fbl[fj] = *(const f16x8*)&Bl[c * 40 + lg * 8];
    }
#pragma unroll
    for (int fi = 0; fi < 2; ++fi)
#pragma unroll
      for (int fj = 0; fj < 2; ++fj) {
        acc[fi][fj] = MFMA16(fah[fi], fbh[fj], acc[fi][fj]);
        acc[fi][fj] = MFMA16(fah[fi], fbl[fj], acc[fi][fj]);
        acc[fi][fj] = MFMA16(fal[fi], fbh[fj], acc[fi][fj]);
      }
    __syncthreads();
  }

  // epilogue: bias, mask, store, deterministic row-sum
  float rp[2][4] = {};
#pragma unroll
  for (int fi = 0; fi < 2; ++fi)
#pragma unroll
    for (int fj = 0; fj < 2; ++fj)
#pragma unroll
      for (int r = 0; r < 4; ++r) {
        int row = wr * 32 + fi * 16 + lg * 4 + r;
        int col = wc * 32 + fj * 16 + lr;
        float v = acc[fi][fj][r] + b2[n0 + col];
        unsigned wd = mlds[row][col >> 5];
        float mv = ((wd >> (col & 31)) & 1u) ? v : 0.f;
        out[(size_t)(m0 + row) * 4096 + (n0 + col)] = mv;
        rp[fi][r] += mv;
      }
#pragma unroll
  for (int fi = 0; fi < 2; ++fi)
#pragma unroll
    for (int r = 0; r < 4; ++r) {
      float s = rp[fi][r];
      s += __shfl_xor(s, 1);
      s += __shfl_xor(s, 2);
      s += __shfl_xor(s, 4);
      s += __shfl_xor(s, 8);
      if (lr == 0) rsum[wr * 32 + fi * 16 + lg * 4 + r][wc] = s;
    }
  __syncthreads();
  if (tid < 64)
    partials[(size_t)(m0 + tid) * 64 + blockIdx.y] = rsum[tid][0] + rsum[tid][1];
}

// ---------- per-row: s = sum(partials), inv = 1/s_safe ----------
__global__ __launch_bounds__(256) void k_rowinv(const float* __restrict__ partials,
                                                float* __restrict__ inv) {
  int r = blockIdx.x * 256 + threadIdx.x;
  if (r < 8192) {
    float s = 0.f;
#pragma unroll 4
    for (int i = 0; i < 64; ++i) s += partials[(size_t)r * 64 + i];
    float ss = (s == 0.f) ? 1.f : s;
    inv[r] = 1.f / ss;
  }
}

// ---------- scale rows in place ----------
__global__ __launch_bounds__(256) void k_scale(float* __restrict__ out,
                                               const float* __restrict__ inv) {
  int v = blockIdx.x * 256 + threadIdx.x;  // 8388608 float4s
  float iv = inv[v >> 10];
  f32x4* p = (f32x4*)out;
  f32x4 d = p[v];
  d[0] *= iv; d[1] *= iv; d[2] *= iv; d[3] *= iv;
  p[v] = d;
}

extern "C" void kernel_launch(void* const* d_in, const int* in_sizes, int n_in,
                              void* d_out, int out_size, void* d_ws, size_t ws_size,
                              hipStream_t stream) {
  const float* x  = (const float*)d_in[0];
  const float* W1 = (const float*)d_in[1];
  const float* b1 = (const float*)d_in[2];
  const float* W2 = (const float*)d_in[3];
  const float* b2 = (const float*)d_in[4];
  float* out = (float*)d_out;
  char* ws = (char*)d_ws;

  f16* W1t_h = (f16*)(ws + (size_t)0);          // [256][4096] fp16 = 2MB
  f16* W1t_l = (f16*)(ws + ((size_t)2 << 20));
  f16* W2t_h = (f16*)(ws + ((size_t)4 << 20));  // [4096][256] fp16 = 2MB
  f16* W2t_l = (f16*)(ws + ((size_t)6 << 20));
  f16* Hh    = (f16*)(ws + ((size_t)8 << 20));  // [8192][256] fp16 = 4MB
  f16* Hl    = (f16*)(ws + ((size_t)12 << 20));
  unsigned char* mb = (unsigned char*)(ws + ((size_t)16 << 20));  // 4MB
  float* partials   = (float*)(ws + ((size_t)20 << 20));          // [8192][64] f32 = 2MB
  float* inv_s      = (float*)(ws + ((size_t)22 << 20));          // 32KB

  // W1 [4096][256] -> W1t [256][4096]; W2 [256][4096] -> W2t [4096][256]
  k_tsplit<<<dim3(4, 64), 256, 0, stream>>>(W1, W1t_h, W1t_l, 4096, 256);
  k_tsplit<<<dim3(64, 4), 256, 0, stream>>>(W2, W2t_h, W2t_l, 256, 4096);
  k_mask<<<16384, 256, 0, stream>>>(x, mb);
  k_gemm1<<<dim3(128, 4), 256, 0, stream>>>(x, W1t_h, W1t_l, b1, Hh, Hl);
  k_gemm2<<<dim3(128, 64), 256, 0, stream>>>(Hh, Hl, W2t_h, W2t_l, b2,
                                             (const unsigned*)mb, out, partials);
  k_rowinv<<<32, 256, 0, stream>>>(partials, inv_s);
  k_scale<<<32768, 256, 0, stream>>>(out, inv_s);
}

// Round 3
// 220.491 us; speedup vs baseline: 1.3609x; 1.3609x over previous
//
#include <hip/hip_runtime.h>

typedef _Float16 f16;
typedef __fp16 h16x2 __attribute__((ext_vector_type(2)));
typedef _Float16 f16x8 __attribute__((ext_vector_type(8)));
typedef float f32x4 __attribute__((ext_vector_type(4)));

#define MFMA16(a,b,c) __builtin_amdgcn_mfma_f32_16x16x32_f16((a),(b),(c),0,0,0)

__device__ __forceinline__ void gload16(const void* g, void* l) {
  __builtin_amdgcn_global_load_lds(
      (const __attribute__((address_space(1))) void*)g,
      (__attribute__((address_space(3))) void*)l, 16, 0, 0);
}

// swizzled f16 offset within a [64 rows][32 k] tile; c = 8-f16 chunk (0..3)
__device__ __forceinline__ int swz(int r, int c) {
  return r * 32 + ((c ^ (r & 3)) << 3);
}

// split v into f16 hi (RTZ) + f16 lo
__device__ __forceinline__ void split8(const f32x4 v0, const f32x4 v1,
                                       f16x8& hv, f16x8& lv) {
  h16x2 h01 = __builtin_amdgcn_cvt_pkrtz(v0[0], v0[1]);
  h16x2 h23 = __builtin_amdgcn_cvt_pkrtz(v0[2], v0[3]);
  h16x2 h45 = __builtin_amdgcn_cvt_pkrtz(v1[0], v1[1]);
  h16x2 h67 = __builtin_amdgcn_cvt_pkrtz(v1[2], v1[3]);
  hv[0] = (f16)h01[0]; hv[1] = (f16)h01[1]; hv[2] = (f16)h23[0]; hv[3] = (f16)h23[1];
  hv[4] = (f16)h45[0]; hv[5] = (f16)h45[1]; hv[6] = (f16)h67[0]; hv[7] = (f16)h67[1];
  h16x2 l01 = __builtin_amdgcn_cvt_pkrtz(v0[0] - (float)h01[0], v0[1] - (float)h01[1]);
  h16x2 l23 = __builtin_amdgcn_cvt_pkrtz(v0[2] - (float)h23[0], v0[3] - (float)h23[1]);
  h16x2 l45 = __builtin_amdgcn_cvt_pkrtz(v1[0] - (float)h45[0], v1[1] - (float)h45[1]);
  h16x2 l67 = __builtin_amdgcn_cvt_pkrtz(v1[2] - (float)h67[0], v1[3] - (float)h67[1]);
  lv[0] = (f16)l01[0]; lv[1] = (f16)l01[1]; lv[2] = (f16)l23[0]; lv[3] = (f16)l23[1];
  lv[4] = (f16)l45[0]; lv[5] = (f16)l45[1]; lv[6] = (f16)l67[0]; lv[7] = (f16)l67[1];
}

// ---------- prep: f32 in[R][C] -> tiled+swizzled fp16 hi/lo B-tiles ----------
// tile t = (c0/64)*(R/32) + k32: [64 n-rows][32 k], 2048 f16 each
__global__ __launch_bounds__(256) void k_prep(const float* __restrict__ in,
                                              f16* __restrict__ oh, f16* __restrict__ ol,
                                              int R, int C) {
  __shared__ float t[64][65];
  int c0 = blockIdx.x * 64, r0 = blockIdx.y * 64;
  int tid = threadIdx.x;
#pragma unroll
  for (int i = 0; i < 16; ++i) {
    int idx = tid + i * 256;
    int r = idx >> 6, c = idx & 63;
    t[r][c] = in[(size_t)(r0 + r) * C + (c0 + c)];
  }
  __syncthreads();
  int tiles_per_col = R >> 5;
#pragma unroll
  for (int w = 0; w < 2; ++w) {
    int idx = tid + w * 256;
    int kt = idx >> 8, rr = (idx >> 2) & 63, cc = idx & 3;
    f32x4 v0, v1;
#pragma unroll
    for (int j = 0; j < 4; ++j) v0[j] = t[kt * 32 + cc * 8 + j][rr];
#pragma unroll
    for (int j = 0; j < 4; ++j) v1[j] = t[kt * 32 + cc * 8 + 4 + j][rr];
    f16x8 hv, lv;
    split8(v0, v1, hv, lv);
    size_t tileIdx = (size_t)(c0 >> 6) * tiles_per_col + (r0 >> 5) + kt;
    size_t off = tileIdx * 2048 + swz(rr, cc);
    *(f16x8*)&oh[off] = hv;
    *(f16x8*)&ol[off] = lv;
  }
}

// ---------- GEMM1: partials[kc] = X[:, kc*2048:+2048] @ W1chunk ----------
// X f32 [8192][4096]; B pre-tiled fp16; also emits mask bytes (nb==0 blocks)
__global__ __launch_bounds__(256, 4) void k_gemm1(
    const float* __restrict__ X, const f16* __restrict__ Bht,
    const f16* __restrict__ Blt, unsigned char* __restrict__ mb,
    float* __restrict__ partials) {
  __shared__ f16 sm[2][4][64 * 32];  // [buf][Ah,Al,Bh,Bl][tile]
  int m0 = blockIdx.x * 64, nb = blockIdx.y, kc = blockIdx.z;
  int tid = threadIdx.x;
  int wv = tid >> 6, ln = tid & 63, lr = ln & 15, lg = ln >> 4;
  int wr = wv >> 1, wc = wv & 1;
  int ar = tid >> 2, ac = tid & 3;
  const int NS = 64;
  int kbase = kc * 2048;
  const float* xrow = X + (size_t)(m0 + ar) * 4096 + kbase + ac * 8;
  size_t btile0 = ((size_t)nb * 128 + (size_t)kc * 64) * 2048;
  bool domask = (nb == 0);
  f32x4 acc[2][2] = {};

  // prologue: stage step 0 into buf 0
  {
    gload16(Bht + btile0 + (size_t)tid * 8, &sm[0][2][wv * 512]);
    gload16(Blt + btile0 + (size_t)tid * 8, &sm[0][3][wv * 512]);
    f32x4 v0 = *(const f32x4*)(xrow);
    f32x4 v1 = *(const f32x4*)(xrow + 4);
    f16x8 hv, lv;
    split8(v0, v1, hv, lv);
    *(f16x8*)&sm[0][0][swz(ar, ac)] = hv;
    *(f16x8*)&sm[0][1][swz(ar, ac)] = lv;
    if (domask) {
      unsigned m = 0;
      if (v0[0] != 0.f) m |= 1u;
      if (v0[1] != 0.f) m |= 2u;
      if (v0[2] != 0.f) m |= 4u;
      if (v0[3] != 0.f) m |= 8u;
      if (v1[0] != 0.f) m |= 16u;
      if (v1[1] != 0.f) m |= 32u;
      if (v1[2] != 0.f) m |= 64u;
      if (v1[3] != 0.f) m |= 128u;
      mb[(size_t)(m0 + ar) * 512 + (kbase >> 3) + ac] = (unsigned char)m;
    }
  }
  __syncthreads();

  int cur = 0;
  for (int s = 0; s < NS; ++s) {
    bool more = (s + 1) < NS;
    f32x4 v0, v1;
    if (more) {
      size_t bt = btile0 + (size_t)(s + 1) * 2048;
      gload16(Bht + bt + (size_t)tid * 8, &sm[cur ^ 1][2][wv * 512]);
      gload16(Blt + bt + (size_t)tid * 8, &sm[cur ^ 1][3][wv * 512]);
      v0 = *(const f32x4*)(xrow + (s + 1) * 32);
      v1 = *(const f32x4*)(xrow + (s + 1) * 32 + 4);
    }
    // compute from buf[cur]
    f16x8 fah[2], fal[2], fbh[2], fbl[2];
#pragma unroll
    for (int fi = 0; fi < 2; ++fi) {
      int r = wr * 32 + fi * 16 + lr;
      fah[fi] = *(const f16x8*)&sm[cur][0][swz(r, lg)];
      fal[fi] = *(const f16x8*)&sm[cur][1][swz(r, lg)];
    }
#pragma unroll
    for (int fj = 0; fj < 2; ++fj) {
      int c = wc * 32 + fj * 16 + lr;
      fbh[fj] = *(const f16x8*)&sm[cur][2][swz(c, lg)];
      fbl[fj] = *(const f16x8*)&sm[cur][3][swz(c, lg)];
    }
#pragma unroll
    for (int fi = 0; fi < 2; ++fi)
#pragma unroll
      for (int fj = 0; fj < 2; ++fj) {
        acc[fi][fj] = MFMA16(fah[fi], fbh[fj], acc[fi][fj]);
        acc[fi][fj] = MFMA16(fah[fi], fbl[fj], acc[fi][fj]);
        acc[fi][fj] = MFMA16(fal[fi], fbh[fj], acc[fi][fj]);
      }
    if (more) {
      f16x8 hv, lv;
      split8(v0, v1, hv, lv);
      *(f16x8*)&sm[cur ^ 1][0][swz(ar, ac)] = hv;
      *(f16x8*)&sm[cur ^ 1][1][swz(ar, ac)] = lv;
      if (domask) {
        unsigned m = 0;
        if (v0[0] != 0.f) m |= 1u;
        if (v0[1] != 0.f) m |= 2u;
        if (v0[2] != 0.f) m |= 4u;
        if (v0[3] != 0.f) m |= 8u;
        if (v1[0] != 0.f) m |= 16u;
        if (v1[1] != 0.f) m |= 32u;
        if (v1[2] != 0.f) m |= 64u;
        if (v1[3] != 0.f) m |= 128u;
        mb[(size_t)(m0 + ar) * 512 + ((kbase + (s + 1) * 32) >> 3) + ac] =
            (unsigned char)m;
      }
    }
    __syncthreads();
    cur ^= 1;
  }

  float* pout = partials + (size_t)kc * 8192 * 256;
#pragma unroll
  for (int fi = 0; fi < 2; ++fi)
#pragma unroll
    for (int fj = 0; fj < 2; ++fj)
#pragma unroll
      for (int r = 0; r < 4; ++r) {
        int row = m0 + wr * 32 + fi * 16 + lg * 4 + r;
        int col = nb * 64 + wc * 32 + fj * 16 + lr;
        pout[(size_t)row * 256 + col] = acc[fi][fj][r];
      }
}

// ---------- reduce split-K + bias + relu + split -> tiled H hi/lo ----------
__global__ __launch_bounds__(256) void k_hsplit(const float* __restrict__ p,
                                                const float* __restrict__ b1,
                                                f16* __restrict__ Hh,
                                                f16* __restrict__ Hl) {
  int g = blockIdx.x * 256 + threadIdx.x;  // 8192*32 = 262144 total
  int r = g >> 5, c = g & 31;
  const float* p0 = p + (size_t)r * 256 + c * 8;
  const float* p1 = p0 + (size_t)8192 * 256;
  f32x4 a0 = *(const f32x4*)p0, a1 = *(const f32x4*)(p0 + 4);
  f32x4 d0 = *(const f32x4*)p1, d1 = *(const f32x4*)(p1 + 4);
  f32x4 bb0 = *(const f32x4*)(b1 + c * 8), bb1 = *(const f32x4*)(b1 + c * 8 + 4);
  f32x4 v0, v1;
#pragma unroll
  for (int j = 0; j < 4; ++j) {
    float v = a0[j] + d0[j] + bb0[j];
    v0[j] = v > 0.f ? v : 0.f;
    float w = a1[j] + d1[j] + bb1[j];
    v1[j] = w > 0.f ? w : 0.f;
  }
  f16x8 hv, lv;
  split8(v0, v1, hv, lv);
  size_t tileIdx = (size_t)(r >> 6) * 8 + (c >> 2);
  size_t off = tileIdx * 2048 + swz(r & 63, c & 3);
  *(f16x8*)&Hh[off] = hv;
  *(f16x8*)&Hl[off] = lv;
}

// ---------- GEMM2: F = H @ W2 + b2, masked store + per-tile row sums ----------
__global__ __launch_bounds__(256, 4) void k_gemm2(
    const f16* __restrict__ At_h, const f16* __restrict__ At_l,
    const f16* __restrict__ Bt_h, const f16* __restrict__ Bt_l,
    const float* __restrict__ b2, const unsigned* __restrict__ maskw,
    float* __restrict__ out, float* __restrict__ partials) {
  __shared__ f16 sm[2][4][64 * 32];
  __shared__ unsigned mlds[64][2];
  __shared__ float rsum[64][2];
  int m0 = blockIdx.x * 64, n0 = blockIdx.y * 64;
  int tid = threadIdx.x;
  int wv = tid >> 6, ln = tid & 63, lr = ln & 15, lg = ln >> 4;
  int wr = wv >> 1, wc = wv & 1;
  if (tid < 128) {
    int r = tid >> 1, w = tid & 1;
    mlds[r][w] = maskw[(size_t)(m0 + r) * 128 + (n0 >> 5) + w];
  }
  size_t atile0 = (size_t)blockIdx.x * 8 * 2048;
  size_t btile0 = (size_t)blockIdx.y * 8 * 2048;
  f32x4 acc[2][2] = {};

  gload16(At_h + atile0 + (size_t)tid * 8, &sm[0][0][wv * 512]);
  gload16(At_l + atile0 + (size_t)tid * 8, &sm[0][1][wv * 512]);
  gload16(Bt_h + btile0 + (size_t)tid * 8, &sm[0][2][wv * 512]);
  gload16(Bt_l + btile0 + (size_t)tid * 8, &sm[0][3][wv * 512]);
  __syncthreads();

  int cur = 0;
  for (int s = 0; s < 8; ++s) {
    bool more = (s + 1) < 8;
    if (more) {
      size_t at = atile0 + (size_t)(s + 1) * 2048;
      size_t bt = btile0 + (size_t)(s + 1) * 2048;
      gload16(At_h + at + (size_t)tid * 8, &sm[cur ^ 1][0][wv * 512]);
      gload16(At_l + at + (size_t)tid * 8, &sm[cur ^ 1][1][wv * 512]);
      gload16(Bt_h + bt + (size_t)tid * 8, &sm[cur ^ 1][2][wv * 512]);
      gload16(Bt_l + bt + (size_t)tid * 8, &sm[cur ^ 1][3][wv * 512]);
    }
    f16x8 fah[2], fal[2], fbh[2], fbl[2];
#pragma unroll
    for (int fi = 0; fi < 2; ++fi) {
      int r = wr * 32 + fi * 16 + lr;
      fah[fi] = *(const f16x8*)&sm[cur][0][swz(r, lg)];
      fal[fi] = *(const f16x8*)&sm[cur][1][swz(r, lg)];
    }
#pragma unroll
    for (int fj = 0; fj < 2; ++fj) {
      int c = wc * 32 + fj * 16 + lr;
      fbh[fj] = *(const f16x8*)&sm[cur][2][swz(c, lg)];
      fbl[fj] = *(const f16x8*)&sm[cur][3][swz(c, lg)];
    }
#pragma unroll
    for (int fi = 0; fi < 2; ++fi)
#pragma unroll
      for (int fj = 0; fj < 2; ++fj) {
        acc[fi][fj] = MFMA16(fah[fi], fbh[fj], acc[fi][fj]);
        acc[fi][fj] = MFMA16(fah[fi], fbl[fj], acc[fi][fj]);
        acc[fi][fj] = MFMA16(fal[fi], fbh[fj], acc[fi][fj]);
      }
    __syncthreads();
    cur ^= 1;
  }

  float rp[2][4] = {};
#pragma unroll
  for (int fi = 0; fi < 2; ++fi)
#pragma unroll
    for (int fj = 0; fj < 2; ++fj)
#pragma unroll
      for (int r = 0; r < 4; ++r) {
        int row = wr * 32 + fi * 16 + lg * 4 + r;
        int col = wc * 32 + fj * 16 + lr;
        float v = acc[fi][fj][r] + b2[n0 + col];
        unsigned wd = mlds[row][col >> 5];
        float mv = ((wd >> (col & 31)) & 1u) ? v : 0.f;
        out[(size_t)(m0 + row) * 4096 + (n0 + col)] = mv;
        rp[fi][r] += mv;
      }
#pragma unroll
  for (int fi = 0; fi < 2; ++fi)
#pragma unroll
    for (int r = 0; r < 4; ++r) {
      float s = rp[fi][r];
      s += __shfl_xor(s, 1);
      s += __shfl_xor(s, 2);
      s += __shfl_xor(s, 4);
      s += __shfl_xor(s, 8);
      if (lr == 0) rsum[wr * 32 + fi * 16 + lg * 4 + r][wc] = s;
    }
  __syncthreads();
  if (tid < 64)
    partials[(size_t)(m0 + tid) * 64 + blockIdx.y] = rsum[tid][0] + rsum[tid][1];
}

// ---------- per-row inverse of masked sum ----------
__global__ __launch_bounds__(256) void k_rowinv(const float* __restrict__ partials,
                                                float* __restrict__ inv) {
  int r = blockIdx.x * 256 + threadIdx.x;
  if (r < 8192) {
    float s = 0.f;
#pragma unroll 4
    for (int i = 0; i < 64; ++i) s += partials[(size_t)r * 64 + i];
    float ss = (s == 0.f) ? 1.f : s;
    inv[r] = 1.f / ss;
  }
}

// ---------- scale rows in place ----------
__global__ __launch_bounds__(256) void k_scale(float* __restrict__ out,
                                               const float* __restrict__ inv) {
  int v = blockIdx.x * 256 + threadIdx.x;
  float iv = inv[v >> 10];
  f32x4* p = (f32x4*)out;
  f32x4 d = p[v];
  d[0] *= iv; d[1] *= iv; d[2] *= iv; d[3] *= iv;
  p[v] = d;
}

extern "C" void kernel_launch(void* const* d_in, const int* in_sizes, int n_in,
                              void* d_out, int out_size, void* d_ws, size_t ws_size,
                              hipStream_t stream) {
  const float* x  = (const float*)d_in[0];
  const float* W1 = (const float*)d_in[1];
  const float* b1 = (const float*)d_in[2];
  const float* W2 = (const float*)d_in[3];
  const float* b2 = (const float*)d_in[4];
  float* out = (float*)d_out;
  char* ws = (char*)d_ws;

  f16* W1t_h = (f16*)(ws + ((size_t)0 << 20));   // 2 MB  (4096*256 f16, tiled)
  f16* W1t_l = (f16*)(ws + ((size_t)2 << 20));
  f16* W2t_h = (f16*)(ws + ((size_t)4 << 20));   // 2 MB
  f16* W2t_l = (f16*)(ws + ((size_t)6 << 20));
  f16* Hh    = (f16*)(ws + ((size_t)8 << 20));   // 4 MB (tiled)
  f16* Hl    = (f16*)(ws + ((size_t)12 << 20));
  unsigned char* mb = (unsigned char*)(ws + ((size_t)16 << 20));  // 4 MB
  float* part1 = (float*)(ws + ((size_t)20 << 20));  // 2 x 8 MB
  float* part2 = (float*)(ws + ((size_t)36 << 20));  // 2 MB
  float* inv_s = (float*)(ws + ((size_t)38 << 20));  // 32 KB

  // W1 [4096 k][256 n] -> tiles; W2 [256 k][4096 n] -> tiles
  k_prep<<<dim3(4, 64), 256, 0, stream>>>(W1, W1t_h, W1t_l, 4096, 256);
  k_prep<<<dim3(64, 4), 256, 0, stream>>>(W2, W2t_h, W2t_l, 256, 4096);
  k_gemm1<<<dim3(128, 4, 2), 256, 0, stream>>>(x, W1t_h, W1t_l, mb, part1);
  k_hsplit<<<1024, 256, 0, stream>>>(part1, b1, Hh, Hl);
  k_gemm2<<<dim3(128, 64), 256, 0, stream>>>(Hh, Hl, W2t_h, W2t_l, b2,
                                             (const unsigned*)mb, out, part2);
  k_rowinv<<<32, 256, 0, stream>>>(part2, inv_s);
  k_scale<<<32768, 256, 0, stream>>>(out, inv_s);
}